// Round 2
// baseline (586.631 us; speedup 1.0000x reference)
//
#include <hip/hip_runtime.h>
#include <hip/hip_bf16.h>
#include <math.h>

typedef __attribute__((ext_vector_type(8))) __bf16 bf16x8;
typedef __attribute__((ext_vector_type(4))) float f32x4;

static __device__ __forceinline__ unsigned short f2bf(float f) {
    unsigned int u = __float_as_uint(f);
    u += 0x7fffu + ((u >> 16) & 1u);   // round-to-nearest-even
    return (unsigned short)(u >> 16);
}

// ---------------------------------------------------------------------------
// K1: row softmax of E -> W in bf16.  One block (256 thr) per row, N=2048.
// ---------------------------------------------------------------------------
__global__ void __launch_bounds__(256) softmax_rows_k(const float* __restrict__ E,
                                                      unsigned short* __restrict__ W,
                                                      int N) {
    __shared__ float red[4];
    const int t = threadIdx.x;
    const int lane = t & 63;
    const int w = t >> 6;
    const size_t row = blockIdx.x;
    const float* e = E + row * (size_t)N;

    float v[8];
    float mx = -3.402823466e38f;
#pragma unroll
    for (int i = 0; i < 8; ++i) { v[i] = e[t + (i << 8)]; mx = fmaxf(mx, v[i]); }
#pragma unroll
    for (int off = 32; off; off >>= 1) mx = fmaxf(mx, __shfl_xor(mx, off));
    if (lane == 0) red[w] = mx;
    __syncthreads();
    mx = fmaxf(fmaxf(red[0], red[1]), fmaxf(red[2], red[3]));
    __syncthreads();

    float s = 0.f;
#pragma unroll
    for (int i = 0; i < 8; ++i) { v[i] = __expf(v[i] - mx); s += v[i]; }
#pragma unroll
    for (int off = 32; off; off >>= 1) s += __shfl_xor(s, off);
    if (lane == 0) red[w] = s;
    __syncthreads();
    s = (red[0] + red[1]) + (red[2] + red[3]);
    const float inv = 1.0f / s;

    unsigned short* o = W + row * (size_t)N;
#pragma unroll
    for (int i = 0; i < 8; ++i) o[t + (i << 8)] = f2bf(v[i] * inv);
}

// ---------------------------------------------------------------------------
// K2: bell = block-diagonal 2x2 linear over adjacent pairs.
//     Writes bell in f32 (exact epilogue term) and bf16 (GEMM A operand).
// ---------------------------------------------------------------------------
__global__ void __launch_bounds__(256) bell_k(const float* __restrict__ spikes,
                                              const float* __restrict__ Wbell,
                                              float* __restrict__ bellf,
                                              unsigned short* __restrict__ bellb,
                                              int N, size_t total4, int write_f32) {
    const size_t stride = (size_t)gridDim.x * blockDim.x;
    const size_t row4 = (size_t)(N >> 2);
    for (size_t i = (size_t)blockIdx.x * blockDim.x + threadIdx.x; i < total4; i += stride) {
        const float4 x = reinterpret_cast<const float4*>(spikes)[i];
        const int c4 = (int)((i % row4) << 2);           // column of first element
        const int p = c4 >> 1;                           // first pair index
        const float4 w0 = reinterpret_cast<const float4*>(Wbell)[p];
        const float4 w1 = reinterpret_cast<const float4*>(Wbell)[p + 1];
        float4 y;
        y.x = w0.x * x.x + w0.y * x.y;
        y.y = w0.z * x.x + w0.w * x.y;
        y.z = w1.x * x.z + w1.y * x.w;
        y.w = w1.z * x.z + w1.w * x.w;
        if (write_f32) reinterpret_cast<float4*>(bellf)[i] = y;
        ushort4 h;
        h.x = f2bf(y.x); h.y = f2bf(y.y); h.z = f2bf(y.z); h.w = f2bf(y.w);
        reinterpret_cast<ushort4*>(bellb)[i] = h;
    }
}

// ---------------------------------------------------------------------------
// K3: C[m,n] = sum_k bell[m,k] * W[n,k]  (bf16 MFMA, m97 structure:
//     128x128 tile, BK=32, 4 waves 2x2, global_load_lds width 16)
//     epilogue: out = clip(0.5*bell_f32 + 0.5*C, 0, 1)
// ---------------------------------------------------------------------------
template <bool BELLF32>
__global__ void __launch_bounds__(256) gemm_entangle_k(
    const unsigned short* __restrict__ A,   // bell bf16 [M][K]
    const unsigned short* __restrict__ Bt,  // W bf16 [N][K] (row n contiguous in k)
    const float* __restrict__ bellf,        // bell f32 [M][K] (if BELLF32)
    const float* __restrict__ spikes,       // [M][K]  (fallback recompute)
    const float* __restrict__ Wbell,        // [K/2][2][2] (fallback recompute)
    float* __restrict__ out,                // entangled [M][N]
    int M, int N, int K) {
    __shared__ unsigned short As[128 * 32];
    __shared__ unsigned short Bs[128 * 32];

    const int tid = threadIdx.x;
    const int lane = tid & 63;
    const int wave = tid >> 6;
    const int wr = wave >> 1;   // 2x2 waves, each 64x64 subtile
    const int wc = wave & 1;

    // XCD-aware bijective swizzle (grid is a multiple of 8)
    const int nwg = gridDim.x;
    const int bid = blockIdx.x;
    int wg;
    if ((nwg & 7) == 0) {
        const int cpx = nwg >> 3;
        wg = (bid & 7) * cpx + (bid >> 3);
    } else {
        wg = bid;
    }
    const int ntn = N >> 7;
    const int tm = wg / ntn;
    const int tn = wg - tm * ntn;
    const size_t m0 = (size_t)tm << 7;
    const size_t n0 = (size_t)tn << 7;

    // staging: each thread covers 16B = 8 bf16; rows tid/4, chunk tid%4
    const int r_a = tid >> 2;
    const int cb = (tid & 3) << 3;

    f32x4 acc[4][4];
#pragma unroll
    for (int i = 0; i < 4; ++i)
#pragma unroll
        for (int j = 0; j < 4; ++j) acc[i][j] = (f32x4)(0.f);

    const unsigned short* ga0 = A + (m0 + r_a) * (size_t)K + cb;
    const unsigned short* ga1 = A + (m0 + 64 + r_a) * (size_t)K + cb;
    const unsigned short* gb0 = Bt + (n0 + r_a) * (size_t)K + cb;
    const unsigned short* gb1 = Bt + (n0 + 64 + r_a) * (size_t)K + cb;

    unsigned short* lA = As + wave * 512;   // wave-uniform LDS base (1024 B/wave)
    unsigned short* lB = Bs + wave * 512;

    const int rsel = lane & 15;
    const int ksel = (lane >> 4) << 3;

    for (int k0 = 0; k0 < K; k0 += 32) {
        __builtin_amdgcn_global_load_lds((const __attribute__((address_space(1))) void*)(ga0 + k0),
                                         (__attribute__((address_space(3))) void*)(lA), 16, 0, 0);
        __builtin_amdgcn_global_load_lds((const __attribute__((address_space(1))) void*)(ga1 + k0),
                                         (__attribute__((address_space(3))) void*)(lA + 2048), 16, 0, 0);
        __builtin_amdgcn_global_load_lds((const __attribute__((address_space(1))) void*)(gb0 + k0),
                                         (__attribute__((address_space(3))) void*)(lB), 16, 0, 0);
        __builtin_amdgcn_global_load_lds((const __attribute__((address_space(1))) void*)(gb1 + k0),
                                         (__attribute__((address_space(3))) void*)(lB + 2048), 16, 0, 0);
        __syncthreads();   // drains vmcnt before LDS reads

        bf16x8 af[4], bfr[4];
#pragma unroll
        for (int i = 0; i < 4; ++i) {
            af[i] = *reinterpret_cast<const bf16x8*>(As + (wr * 64 + i * 16 + rsel) * 32 + ksel);
            bfr[i] = *reinterpret_cast<const bf16x8*>(Bs + (wc * 64 + i * 16 + rsel) * 32 + ksel);
        }
#pragma unroll
        for (int i = 0; i < 4; ++i)
#pragma unroll
            for (int j = 0; j < 4; ++j)
                acc[i][j] = __builtin_amdgcn_mfma_f32_16x16x32_bf16(af[i], bfr[j], acc[i][j], 0, 0, 0);
        __syncthreads();
    }

    // epilogue: entangled = clip(0.5*bell + 0.5*nonlocal, 0, 1)
#pragma unroll
    for (int i = 0; i < 4; ++i) {
        const int rbase = wr * 64 + i * 16 + ((lane >> 4) << 2);
#pragma unroll
        for (int j = 0; j < 4; ++j) {
            const int col = (int)n0 + wc * 64 + j * 16 + (lane & 15);
#pragma unroll
            for (int r = 0; r < 4; ++r) {
                const size_t row = m0 + rbase + r;
                float bv;
                if constexpr (BELLF32) {
                    bv = bellf[row * (size_t)K + col];
                } else {
                    const int p2 = col & ~1;
                    const float s0v = spikes[row * (size_t)K + p2];
                    const float s1v = spikes[row * (size_t)K + p2 + 1];
                    const float* wp = Wbell + ((size_t)(col >> 1) << 2) + ((col & 1) << 1);
                    bv = wp[0] * s0v + wp[1] * s1v;
                }
                float ev = 0.5f * bv + 0.5f * acc[i][j][r];
                ev = fminf(fmaxf(ev, 0.f), 1.f);
                out[row * (size_t)N + col] = ev;
            }
        }
    }
}

// ---------------------------------------------------------------------------
// K4: vectorized cosine similarity per row + mean(|.|) via one atomic/block.
//     dot(oc,ec) = sse - ss*se/N ; |oc|^2 = sss - ss^2/N  (single pass)
// ---------------------------------------------------------------------------
__global__ void __launch_bounds__(256) corr_k(const float* __restrict__ spikes,
                                              const float* __restrict__ ent,
                                              float* __restrict__ corr_out,
                                              int Brows, int N, float scale) {
    __shared__ float wsum[4];
    const int lane = threadIdx.x & 63;
    const int w = threadIdx.x >> 6;
    const int n4 = N >> 2;
    float local = 0.f;

    for (int row = blockIdx.x * 4 + w; row < Brows; row += gridDim.x * 4) {
        const float4* s = reinterpret_cast<const float4*>(spikes + (size_t)row * N);
        const float4* e = reinterpret_cast<const float4*>(ent + (size_t)row * N);
        float ss = 0.f, se = 0.f, sss = 0.f, see = 0.f, sse = 0.f;
        for (int i = lane; i < n4; i += 64) {
            const float4 a = s[i];
            const float4 b = e[i];
            ss += (a.x + a.y) + (a.z + a.w);
            se += (b.x + b.y) + (b.z + b.w);
            sss += (a.x * a.x + a.y * a.y) + (a.z * a.z + a.w * a.w);
            see += (b.x * b.x + b.y * b.y) + (b.z * b.z + b.w * b.w);
            sse += (a.x * b.x + a.y * b.y) + (a.z * b.z + a.w * b.w);
        }
#pragma unroll
        for (int off = 32; off; off >>= 1) {
            ss += __shfl_xor(ss, off);
            se += __shfl_xor(se, off);
            sss += __shfl_xor(sss, off);
            see += __shfl_xor(see, off);
            sse += __shfl_xor(sse, off);
        }
        if (lane == 0) {
            const float n = (float)N;
            const float dot = sse - ss * se / n;
            const float na2 = fmaxf(sss - ss * ss / n, 0.f);
            const float nb2 = fmaxf(see - se * se / n, 0.f);
            const float na = fmaxf(sqrtf(na2), 1e-8f);
            const float nb = fmaxf(sqrtf(nb2), 1e-8f);
            local += fabsf(dot / (na * nb));
        }
    }
    if (lane == 0) wsum[w] = local;
    __syncthreads();
    if (threadIdx.x == 0)
        atomicAdd(corr_out, ((wsum[0] + wsum[1]) + (wsum[2] + wsum[3])) * scale);
}

// ---------------------------------------------------------------------------
extern "C" void kernel_launch(void* const* d_in, const int* in_sizes, int n_in,
                              void* d_out, int out_size, void* d_ws, size_t ws_size,
                              hipStream_t stream) {
    const float* spikes = (const float*)d_in[0];
    const float* Wbell = (const float*)d_in[1];
    const float* E = (const float*)d_in[2];
    float* outf = (float*)d_out;

    const int N = (int)(sqrt((double)in_sizes[2]) + 0.5);
    const int Brows = in_sizes[0] / N;

    // workspace: W_bf16 [N*N] | bell_bf16 [B*N] | bell_f32 [B*N] (optional)
    unsigned short* Wb = (unsigned short*)d_ws;
    unsigned short* bellb = Wb + (size_t)N * N;
    size_t used = (size_t)N * N * sizeof(unsigned short) +
                  (size_t)Brows * N * sizeof(unsigned short);
    float* bellf = (float*)((char*)d_ws + used);
    const bool have_f32 = (used + (size_t)Brows * N * sizeof(float)) <= ws_size;

    softmax_rows_k<<<N, 256, 0, stream>>>(E, Wb, N);

    const size_t total4 = ((size_t)Brows * N) >> 2;
    bell_k<<<4096, 256, 0, stream>>>(spikes, Wbell, have_f32 ? bellf : nullptr, bellb,
                                     N, total4, have_f32 ? 1 : 0);

    // zero the bell_corr accumulator slot (d_out is poisoned each launch)
    hipMemsetAsync(outf + (size_t)Brows * N, 0, sizeof(float), stream);

    const int nblocks = (Brows >> 7) * (N >> 7);
    if (have_f32)
        gemm_entangle_k<true><<<nblocks, 256, 0, stream>>>(bellb, Wb, bellf, spikes, Wbell,
                                                           outf, Brows, N, N);
    else
        gemm_entangle_k<false><<<nblocks, 256, 0, stream>>>(bellb, Wb, nullptr, spikes, Wbell,
                                                            outf, Brows, N, N);

    corr_k<<<1024, 256, 0, stream>>>(spikes, outf, outf + (size_t)Brows * N,
                                     Brows, N, 1.0f / (float)Brows);
}